// Round 2
// baseline (915.190 us; speedup 1.0000x reference)
//
#include <hip/hip_runtime.h>

// ---------------- problem constants ----------------
#define B_    64
#define S_    512
#define V_    50257
#define E_    512
#define H_    1024
#define OOV_  12
#define VO_   (V_ + OOV_)     // 50269
#define NTOT_ (V_ + S_)       // 50769

typedef float  f32x4  __attribute__((ext_vector_type(4)));
typedef __bf16 bf16x8 __attribute__((ext_vector_type(8)));
typedef unsigned short ushort8 __attribute__((ext_vector_type(8)));

__device__ __forceinline__ unsigned short f2bf(float f) {
  union { float f; unsigned u; } c; c.f = f;
  unsigned r = c.u + 0x7FFFu + ((c.u >> 16) & 1u);   // RNE
  return (unsigned short)(r >> 16);
}
__device__ __forceinline__ ushort8 cvt8(float4 u0, float4 u1) {
  ushort8 p;
  p[0] = f2bf(u0.x); p[1] = f2bf(u0.y); p[2] = f2bf(u0.z); p[3] = f2bf(u0.w);
  p[4] = f2bf(u1.x); p[5] = f2bf(u1.y); p[6] = f2bf(u1.z); p[7] = f2bf(u1.w);
  return p;
}

// ---------------- fp32 -> bf16 conversion pass ----------------
__global__ __launch_bounds__(256)
void cvt_bf16(const float* __restrict__ in, unsigned short* __restrict__ out, int n8)
{
  int i = blockIdx.x * 256 + threadIdx.x;
  const int stride = gridDim.x * 256;
  for (; i < n8; i += stride) {
    float4 u0 = ((const float4*)in)[2 * i];
    float4 u1 = ((const float4*)in)[2 * i + 1];
    ((ushort8*)out)[i] = cvt8(u0, u1);
  }
}

// build x = [embed[input_idx[m]], weighted[m]]  as bf16 (64 x 2560)
__global__ __launch_bounds__(256)
void build_x(const int* __restrict__ idx, const float* __restrict__ embed,
             const float* __restrict__ weighted, unsigned short* __restrict__ xb)
{
  const int t = blockIdx.x * 256 + threadIdx.x;     // 64*320
  if (t >= B_ * 320) return;
  const int m = t / 320, k = (t % 320) * 8;
  const float* src = (k < E_) ? &embed[(size_t)idx[m] * E_ + k]
                              : &weighted[(size_t)m * (2 * H_) + (k - E_)];
  float4 u0 = *(const float4*)src;
  float4 u1 = *(const float4*)(src + 4);
  ((ushort8*)xb)[t] = cvt8(u0, u1);
}

// ---------------- bf16 MFMA GEMM, m97-style staging (small/medium GEMMs) ----
#define TILE 128
#define BK   64

template<int MODE, int ACVT, int BCVT, int XSWZ>
__global__ __launch_bounds__(256)
void gemm_bf(const unsigned short* __restrict__ Ab, const float* __restrict__ Af,
             const unsigned short* __restrict__ Bb, const float* __restrict__ Bf,
             const float* __restrict__ bias, const float* __restrict__ statev,
             float* __restrict__ out, int M, int N, int K, int ntn, int Kc)
{
  __shared__ unsigned short lds_a[TILE * BK];
  __shared__ unsigned short lds_b[TILE * BK];

  const int tid  = threadIdx.x;
  const int bid  = blockIdx.x;
  int m0, n0;
  if (XSWZ) {
    const int cpx = gridDim.x >> 6;
    const int xcd = bid & 7, s = bid >> 3;
    m0 = (xcd * cpx + (s >> 3)) * TILE;
    n0 = (s & 7) * TILE;
  } else {
    m0 = (bid / ntn) * TILE;
    n0 = (bid % ntn) * TILE;
  }

  const int lane = tid & 63;
  const int wave = tid >> 6;
  const int wrow = wave >> 1, wcol = wave & 1;
  const int lm   = lane & 15, quad = lane >> 4;

  f32x4 acc[4][4];
  #pragma unroll
  for (int i = 0; i < 4; ++i)
    #pragma unroll
    for (int j = 0; j < 4; ++j) { f32x4 z = {0.f, 0.f, 0.f, 0.f}; acc[i][j] = z; }

  const int k0   = blockIdx.y * Kc;
  const int kend = min(k0 + Kc, K);

  for (int kt = k0; kt < kend; kt += BK) {
    if (ACVT) {
      const int r = tid >> 1;
      const int grow = min(m0 + r, M - 1);
      const float* __restrict__ base = &Af[(size_t)grow * K + kt];
      #pragma unroll
      for (int q = 0; q < 4; ++q) {
        const int j = (tid & 1) * 4 + q;
        float4 u0 = *(const float4*)(base + j * 8);
        float4 u1 = *(const float4*)(base + j * 8 + 4);
        *(ushort8*)&lds_a[r * BK + (j ^ (r & 7)) * 8] = cvt8(u0, u1);
      }
    } else {
      #pragma unroll
      for (int t = 0; t < 4; ++t) {
        const int r  = (wave * 4 + t) * 8 + (lane >> 3);
        const int jg = (lane & 7) ^ (r & 7);
        const int grow = min(m0 + r, M - 1);
        const unsigned short* g = &Ab[(size_t)grow * K + kt + jg * 8];
        __builtin_amdgcn_global_load_lds(
            (const __attribute__((address_space(1))) void*)g,
            (__attribute__((address_space(3))) void*)&lds_a[(wave * 4 + t) * 512],
            16, 0, 0);
      }
    }
    if (BCVT) {
      const int r = tid >> 1;
      const int grow = min(n0 + r, N - 1);
      const float* __restrict__ base = &Bf[(size_t)grow * K + kt];
      #pragma unroll
      for (int q = 0; q < 4; ++q) {
        const int j = (tid & 1) * 4 + q;
        float4 u0 = *(const float4*)(base + j * 8);
        float4 u1 = *(const float4*)(base + j * 8 + 4);
        *(ushort8*)&lds_b[r * BK + (j ^ (r & 7)) * 8] = cvt8(u0, u1);
      }
    } else {
      #pragma unroll
      for (int t = 0; t < 4; ++t) {
        const int r  = (wave * 4 + t) * 8 + (lane >> 3);
        const int jg = (lane & 7) ^ (r & 7);
        const int grow = min(n0 + r, N - 1);
        const unsigned short* g = &Bb[(size_t)grow * K + kt + jg * 8];
        __builtin_amdgcn_global_load_lds(
            (const __attribute__((address_space(1))) void*)g,
            (__attribute__((address_space(3))) void*)&lds_b[(wave * 4 + t) * 512],
            16, 0, 0);
      }
    }
    __syncthreads();

    #pragma unroll
    for (int ks = 0; ks < BK; ks += 32) {
      const int c0 = ks >> 3;
      bf16x8 av[4], bv[4];
      #pragma unroll
      for (int i = 0; i < 4; ++i) {
        const int r = wrow * 64 + i * 16 + lm;
        av[i] = *(const bf16x8*)&lds_a[r * BK + (((c0 + quad) ^ (lm & 7)) * 8)];
      }
      #pragma unroll
      for (int j = 0; j < 4; ++j) {
        const int r = wcol * 64 + j * 16 + lm;
        bv[j] = *(const bf16x8*)&lds_b[r * BK + (((c0 + quad) ^ (lm & 7)) * 8)];
      }
      #pragma unroll
      for (int i = 0; i < 4; ++i)
        #pragma unroll
        for (int j = 0; j < 4; ++j)
          acc[i][j] = __builtin_amdgcn_mfma_f32_16x16x32_bf16(av[i], bv[j], acc[i][j], 0, 0, 0);
    }
    __syncthreads();
  }

  if (MODE == 0) {
    #pragma unroll
    for (int i = 0; i < 4; ++i) {
      const int rbase = m0 + wrow * 64 + i * 16 + quad * 4;
      #pragma unroll
      for (int j = 0; j < 4; ++j) {
        const int col = n0 + wcol * 64 + j * 16 + lm;
        if (col < N) {
          const float bv2 = bias[col];
          #pragma unroll
          for (int r = 0; r < 4; ++r) {
            const int row = rbase + r;
            if (row < M) out[(size_t)row * N + col] = acc[i][j][r] + bv2;
          }
        }
      }
    }
  } else if (MODE == 1) {
    float* rowsum = (float*)lds_b;
    if (tid < TILE) rowsum[tid] = 0.f;
    __syncthreads();
    #pragma unroll
    for (int i = 0; i < 4; ++i) {
      #pragma unroll
      for (int r = 0; r < 4; ++r) {
        const int rloc = wrow * 64 + i * 16 + quad * 4 + r;
        const int row  = m0 + rloc;
        const int b    = row >> 9;
        float p = 0.f;
        #pragma unroll
        for (int j = 0; j < 4; ++j) {
          const int col = wcol * 64 + j * 16 + lm;
          const float v = acc[i][j][r] + bias[col];
          p += tanhf(v) * statev[b * H_ + col];
        }
        p += __shfl_xor(p, 1);
        p += __shfl_xor(p, 2);
        p += __shfl_xor(p, 4);
        p += __shfl_xor(p, 8);
        if (lm == 0) atomicAdd(&rowsum[rloc], p);
      }
    }
    __syncthreads();
    if (tid < TILE) atomicAdd(&out[m0 + tid], rowsum[tid]);
  } else {
    #pragma unroll
    for (int i = 0; i < 4; ++i) {
      const int rbase = m0 + wrow * 64 + i * 16 + quad * 4;
      #pragma unroll
      for (int j = 0; j < 4; ++j) {
        const int col = n0 + wcol * 64 + j * 16 + lm;
        if (col < N) {
          #pragma unroll
          for (int r = 0; r < 4; ++r) {
            const int row = rbase + r;
            if (row < M) atomicAdd(&out[(size_t)row * N + col], acc[i][j][r]);
          }
        }
      }
    }
  }
}

// ---------------- 256^2-tile 4-phase counted-vmcnt GEMM for acc_c ----------
// C(32768,1024) = A(32768,2048) @ B(1024,2048)^T, fused tanh*state row-reduce.
// 8 waves (2M x 4N); per-wave out = rows {wr*64..+64} u {128+wr*64..+64},
// cols {wc*32..+32} u {128+wc*32..+32}  -> LDS halves free progressively.
// Per K-tile: 4 quadrant phases; stage 1 half-tile of tile t+1 per phase.
// Steady-state waits: vmcnt(6) @P1, vmcnt(4) @P2 -- never 0 in main loop.
#define READ_A256(la, rbase)                                                   \
  { _Pragma("unroll") for (int fi = 0; fi < 4; ++fi)                           \
    _Pragma("unroll") for (int k = 0; k < 2; ++k) {                            \
      const int r = (rbase) + fi * 16 + lm;                                    \
      af[fi][k] = *(const bf16x8*)&(la)[r * 64 + (((k * 4 + quad) ^ (lm & 7)) * 8)]; } }

#define READ_B256(lb, rbase, BB)                                               \
  { _Pragma("unroll") for (int fj = 0; fj < 2; ++fj)                           \
    _Pragma("unroll") for (int k = 0; k < 2; ++k) {                            \
      const int r = (rbase) + fj * 16 + lm;                                    \
      BB[fj][k] = *(const bf16x8*)&(lb)[r * 64 + (((k * 4 + quad) ^ (lm & 7)) * 8)]; } }

#define MFMA_QUAD(rh, ch, BB)                                                  \
  { __builtin_amdgcn_s_setprio(1);                                            \
    _Pragma("unroll") for (int fi = 0; fi < 4; ++fi)                           \
    _Pragma("unroll") for (int fj = 0; fj < 2; ++fj)                           \
    _Pragma("unroll") for (int k = 0; k < 2; ++k)                              \
      acc[rh][fi][ch][fj] = __builtin_amdgcn_mfma_f32_16x16x32_bf16(           \
          af[fi][k], BB[fj][k], acc[rh][fi][ch][fj], 0, 0, 0);                 \
    __builtin_amdgcn_s_setprio(0); }

#define BAR256() { __builtin_amdgcn_s_barrier(); asm volatile("" ::: "memory"); }

__global__ __launch_bounds__(512)
void gemm256_accc(const unsigned short* __restrict__ A,   // 32768 x 2048 bf16
                  const unsigned short* __restrict__ Bw,  // 1024 x 2048 bf16
                  const float* __restrict__ bias,         // 1024
                  const float* __restrict__ statev,       // 64 x 1024
                  float* __restrict__ out)                // 32768, pre-zeroed
{
  __shared__ unsigned short lds_a[2][256 * 64];   // 2 x 32 KB
  __shared__ unsigned short lds_b[2][256 * 64];   // 2 x 32 KB  (total 128 KB)
  __shared__ float rowsum[256];

  const int tid = threadIdx.x;
  const int bid = blockIdx.x;
  // XCD-aware: 512 blocks = 8 xcds x (16 m-tiles x 4 n-tiles); bijective.
  const int xcd = bid & 7, s = bid >> 3;
  const int m0 = (xcd * 16 + (s >> 2)) * 256;
  const int n0 = (s & 3) * 256;

  const int lane = tid & 63;
  const int wave = tid >> 6;          // 0..7
  const int wr   = wave >> 2;         // 0..1
  const int wc   = wave & 3;          // 0..3
  const int lm   = lane & 15, quad = lane >> 4;

  // staging geometry: per gload i in {0,1}: row = i*64 + (tid>>3), LDS chunk
  // (tid&7) holds global chunk (tid&7)^(row&7)  (chunk-XOR swizzle, 0-conflict)
  const int srow = tid >> 3;
  const int jg   = (tid & 7) ^ (srow & 7);

  if (tid < 256) rowsum[tid] = 0.f;

  f32x4 acc[2][4][2][2];
  #pragma unroll
  for (int rh = 0; rh < 2; ++rh)
    #pragma unroll
    for (int fi = 0; fi < 4; ++fi)
      #pragma unroll
      for (int ch = 0; ch < 2; ++ch)
        #pragma unroll
        for (int fj = 0; fj < 2; ++fj) { f32x4 z = {0.f,0.f,0.f,0.f}; acc[rh][fi][ch][fj] = z; }

  const unsigned short* A0 = A  + (size_t)m0 * 2048;
  const unsigned short* B0 = Bw + (size_t)n0 * 2048;

  auto stage_half = [&](const unsigned short* gbase, int grow0,
                        unsigned short* lbase, int kabs) {
    #pragma unroll
    for (int i = 0; i < 2; ++i) {
      const int r = i * 64 + srow;
      const unsigned short* g = gbase + (size_t)(grow0 + r) * 2048 + kabs + jg * 8;
      __builtin_amdgcn_global_load_lds(
          (const __attribute__((address_space(1))) void*)g,
          (__attribute__((address_space(3))) void*)(lbase + i * 4096 + wave * 512),
          16, 0, 0);
    }
  };

  bf16x8 af[4][2], bl[2][2], bh[2][2];

  // prologue: tile 0, issue order A-lo, B-lo, A-hi, B-hi (matches steady state)
  stage_half(A0, 0,   lds_a[0],        0);
  stage_half(B0, 0,   lds_b[0],        0);
  stage_half(A0, 128, lds_a[0] + 8192, 0);
  stage_half(B0, 128, lds_b[0] + 8192, 0);

  for (int t = 0; t < 31; ++t) {
    const int cur = t & 1, nb = cur ^ 1;
    const int kn  = (t + 1) * 64;
    unsigned short* la_c = lds_a[cur];
    unsigned short* lb_c = lds_b[cur];

    // P1: quadrant (row-lo, col-lo)
    stage_half(A0, 0, lds_a[nb], kn);                 // A-lo(t+1)
    asm volatile("s_waitcnt vmcnt(6)" ::: "memory");  // A-lo(t), B-lo(t) landed
    BAR256();
    READ_A256(la_c, wr * 64);
    READ_B256(lb_c, wc * 32, bl);
    MFMA_QUAD(0, 0, bl);

    // P2: quadrant (row-lo, col-hi)
    stage_half(B0, 0, lds_b[nb], kn);                 // B-lo(t+1)
    asm volatile("s_waitcnt vmcnt(4)" ::: "memory");  // A-hi(t), B-hi(t) landed
    BAR256();
    READ_B256(lb_c, 128 + wc * 32, bh);
    MFMA_QUAD(0, 1, bh);

    // P3: quadrant (row-hi, col-lo)
    stage_half(A0, 128, lds_a[nb] + 8192, kn);        // A-hi(t+1)
    BAR256();
    READ_A256(la_c, 128 + wr * 64);
    MFMA_QUAD(1, 0, bl);

    // P4: quadrant (row-hi, col-hi)
    stage_half(B0, 128, lds_b[nb] + 8192, kn);        // B-hi(t+1)
    BAR256();
    MFMA_QUAD(1, 1, bh);
  }

  { // peeled last tile t = 31 (cur = 1), no stages, drain allowed
    unsigned short* la_c = lds_a[1];
    unsigned short* lb_c = lds_b[1];

    asm volatile("s_waitcnt vmcnt(4)" ::: "memory");
    BAR256();
    READ_A256(la_c, wr * 64);
    READ_B256(lb_c, wc * 32, bl);
    MFMA_QUAD(0, 0, bl);

    asm volatile("s_waitcnt vmcnt(0)" ::: "memory");
    BAR256();
    READ_B256(lb_c, 128 + wc * 32, bh);
    MFMA_QUAD(0, 1, bh);

    BAR256();
    READ_A256(la_c, 128 + wr * 64);
    MFMA_QUAD(1, 0, bl);

    BAR256();
    MFMA_QUAD(1, 1, bh);
  }

  // fused epilogue: p[row] = sum_col tanh(acc + bias[col]) * state[b, col]
  __syncthreads();
  #pragma unroll
  for (int rh = 0; rh < 2; ++rh)
    #pragma unroll
    for (int fi = 0; fi < 4; ++fi)
      #pragma unroll
      for (int r = 0; r < 4; ++r) {
        const int rloc = rh * 128 + wr * 64 + fi * 16 + quad * 4 + r;
        const int grow = m0 + rloc;
        const int b    = grow >> 9;
        float p = 0.f;
        #pragma unroll
        for (int ch = 0; ch < 2; ++ch)
          #pragma unroll
          for (int fj = 0; fj < 2; ++fj) {
            const int col = n0 + ch * 128 + wc * 32 + fj * 16 + lm;
            const float v = acc[rh][fi][ch][fj][r] + bias[col];
            p += tanhf(v) * statev[b * H_ + col];
          }
        p += __shfl_xor(p, 1);
        p += __shfl_xor(p, 2);
        p += __shfl_xor(p, 4);
        p += __shfl_xor(p, 8);
        if (lm == 0) atomicAdd(&rowsum[rloc], p);
      }
  __syncthreads();
  if (tid < 256) atomicAdd(&out[m0 + tid], rowsum[tid]);
}

// ---------------- GRU gate combine (+ bf16 state copy) ----------------
__global__ __launch_bounds__(256)
void gru_combine(const float* __restrict__ gis, const float* __restrict__ ghs,
                 const float* __restrict__ prev, float* __restrict__ state,
                 unsigned short* __restrict__ st_bf,
                 const float* __restrict__ bi, const float* __restrict__ bh)
{
  const int idx = blockIdx.x * 256 + threadIdx.x;
  const int b = idx >> 10, h = idx & (H_ - 1);
  const float* gib = gis + (size_t)b * 3 * H_;
  const float* ghb = ghs + (size_t)b * 3 * H_;
  const float gr = gib[h]          + bi[h];
  const float hr = ghb[h]          + bh[h];
  const float gz = gib[H_ + h]     + bi[H_ + h];
  const float hz = ghb[H_ + h]     + bh[H_ + h];
  const float gn = gib[2 * H_ + h] + bi[2 * H_ + h];
  const float hn = ghb[2 * H_ + h] + bh[2 * H_ + h];
  const float r = 1.f / (1.f + expf(-(gr + hr)));
  const float z = 1.f / (1.f + expf(-(gz + hz)));
  const float n = tanhf(gn + r * hn);
  const float s = (1.f - z) * n + z * prev[idx];
  state[idx] = s;
  st_bf[idx] = f2bf(s);
}

// ---------------- softmax (chunked two-phase) ----------------
#define CH  2048
#define NCH 25

__global__ __launch_bounds__(256)
void softmax_chunk(const float* __restrict__ score_g, const float* __restrict__ acc_c,
                   const int* __restrict__ eidx, float* __restrict__ mc, float* __restrict__ lc)
{
  const int b = blockIdx.y, c = blockIdx.x, tid = threadIdx.x;
  const int start = c * CH;
  const int end   = min(start + CH, NTOT_);
  __shared__ float red[4];

  float lmax = -1e30f;
  for (int i = start + tid; i < end; i += 256) {
    float v;
    if (i < V_) v = score_g[(size_t)b * V_ + i];
    else {
      const int s = i - V_;
      v = tanhf(acc_c[b * S_ + s]) + (eidx[b * S_ + s] == 0 ? -1000.f : 0.f);
    }
    lmax = fmaxf(lmax, v);
  }
  #pragma unroll
  for (int o = 32; o > 0; o >>= 1) lmax = fmaxf(lmax, __shfl_xor(lmax, o));
  if ((tid & 63) == 0) red[tid >> 6] = lmax;
  __syncthreads();
  lmax = fmaxf(fmaxf(red[0], red[1]), fmaxf(red[2], red[3]));
  __syncthreads();

  float lsum = 0.f;
  for (int i = start + tid; i < end; i += 256) {
    float v;
    if (i < V_) v = score_g[(size_t)b * V_ + i];
    else {
      const int s = i - V_;
      v = tanhf(acc_c[b * S_ + s]) + (eidx[b * S_ + s] == 0 ? -1000.f : 0.f);
    }
    lsum += expf(v - lmax);
  }
  #pragma unroll
  for (int o = 32; o > 0; o >>= 1) lsum += __shfl_xor(lsum, o);
  if ((tid & 63) == 0) red[tid >> 6] = lsum;
  __syncthreads();
  if (tid == 0) {
    mc[b * NCH + c] = lmax;
    lc[b * NCH + c] = red[0] + red[1] + red[2] + red[3];
  }
}

// ---------------- prob_g + OOV write (M/invL inline from mc/lc) ------------
__global__ __launch_bounds__(256)
void write_probg(const float* __restrict__ score_g, const float* __restrict__ mc,
                 const float* __restrict__ lc, float* __restrict__ out)
{
  __shared__ float sM, sIL;
  const int b = blockIdx.y, tid = threadIdx.x;
  if (tid == 0) {
    float M = -1e30f;
    for (int c = 0; c < NCH; ++c) M = fmaxf(M, mc[b * NCH + c]);
    float L = 0.f;
    for (int c = 0; c < NCH; ++c) L += lc[b * NCH + c] * expf(mc[b * NCH + c] - M);
    sM = M; sIL = 1.f / L;
  }
  __syncthreads();
  const int v = blockIdx.x * 256 + tid;
  if (v >= VO_) return;
  float val;
  if (v < V_) val = expf(score_g[(size_t)b * V_ + v] - sM) * sIL;
  else        val = 1e-4f;
  out[(size_t)b * VO_ + v] = val;
}

// ---------------- prob_c scatter + attention-weighted sum ----------------
__global__ __launch_bounds__(256)
void scatter_weighted(const float* __restrict__ acc_c, const int* __restrict__ eidx,
                      const int* __restrict__ input_idx, const float* __restrict__ encoded,
                      const float* __restrict__ mc, const float* __restrict__ lc,
                      float* __restrict__ out, float* __restrict__ wout)
{
  __shared__ float pv[S_];
  __shared__ int   mlist[S_];
  __shared__ int   mcnt;
  __shared__ float sM, sIL;
  const int b = blockIdx.x, tid = threadIdx.x;
  if (tid == 0) {
    mcnt = 0;
    float M = -1e30f;
    for (int c = 0; c < NCH; ++c) M = fmaxf(M, mc[b * NCH + c]);
    float L = 0.f;
    for (int c = 0; c < NCH; ++c) L += lc[b * NCH + c] * expf(mc[b * NCH + c] - M);
    sM = M; sIL = 1.f / L;
  }
  __syncthreads();

  const int   ii = input_idx[b];
  const float M  = sM, il = sIL;
  for (int s = tid; s < S_; s += 256) {
    const int e = eidx[b * S_ + s];
    const float v = tanhf(acc_c[b * S_ + s]) + (e == 0 ? -1000.f : 0.f);
    const float p = expf(v - M) * il;
    pv[s] = p;
    atomicAdd(&out[(size_t)b * VO_ + e], p);
    if (e == ii) { const int pos = atomicAdd(&mcnt, 1); mlist[pos] = s; }
  }
  __syncthreads();

  const int cnt = mcnt;
  const float norm = cnt > 1 ? 1.f / (float)cnt : 1.f;
  for (int d = tid; d < 2 * H_; d += 256) {
    float a = 0.f;
    for (int t2 = 0; t2 < cnt; ++t2) {
      const int s = mlist[t2];
      a += pv[s] * encoded[((size_t)b * S_ + s) * (2 * H_) + d];
    }
    wout[(size_t)b * 2 * H_ + d] = a * norm;
  }
}

// ---------------- host launcher ----------------
extern "C" void kernel_launch(void* const* d_in, const int* in_sizes, int n_in,
                              void* d_out, int out_size, void* d_ws, size_t ws_size,
                              hipStream_t stream)
{
  const int*   input_idx   = (const int*)  d_in[0];
  const float* encoded     = (const float*)d_in[1];
  const int*   encoded_idx = (const int*)  d_in[2];
  const float* prev_state  = (const float*)d_in[3];
  const float* weighted    = (const float*)d_in[4];
  const float* embed       = (const float*)d_in[6];
  const float* gru_wi      = (const float*)d_in[7];
  const float* gru_wh      = (const float*)d_in[8];
  const float* gru_bi      = (const float*)d_in[9];
  const float* gru_bh      = (const float*)d_in[10];
  const float* Wg_w        = (const float*)d_in[13];
  const float* Wg_b        = (const float*)d_in[14];
  const float* Wc_w        = (const float*)d_in[15];
  const float* Wc_b        = (const float*)d_in[16];

  float* out0  = (float*)d_out;                    // (64, 1, 50269)
  float* state = out0 + (size_t)B_ * VO_;          // (64, 1024)
  float* wout  = state + (size_t)B_ * H_;          // (64, 1, 2048)

  // ---- ws layout: f32 region, then bf16 region (tiered by ws_size) ----
  float* score_g = (float*)d_ws;                    // 64*50257
  float* gis     = score_g + (size_t)B_ * V_;       // 64*3072
  float* ghs     = gis + (size_t)B_ * 3 * H_;
  float* acc_c   = ghs + (size_t)B_ * 3 * H_;       // 64*512
  float* mc      = acc_c + (size_t)B_ * S_;
  float* lc      = mc + B_ * NCH;

  unsigned short* ub = (unsigned short*)(lc + B_ * NCH);
  ub = (unsigned short*)(((uintptr_t)ub + 15) & ~(uintptr_t)15);
  unsigned short* x_bf  = ub;  ub += (size_t)B_ * (E_ + 2 * H_);   // 163840
  unsigned short* ps_bf = ub;  ub += (size_t)B_ * H_;
  unsigned short* st_bf = ub;  ub += (size_t)B_ * H_;
  unsigned short* wc_bf = ub;
  unsigned short* wi_bf = wc_bf + (size_t)H_ * 2 * H_;
  unsigned short* wh_bf = wi_bf + (size_t)3 * H_ * (E_ + 2 * H_);
  unsigned short* end_small = wh_bf + (size_t)3 * H_ * H_;
  unsigned short* wg_bf  = end_small;
  unsigned short* end_wg = wg_bf + (size_t)V_ * H_;
  unsigned short* enc_bf = end_wg;
  unsigned short* end_enc = enc_bf + (size_t)B_ * S_ * 2 * H_;

  const bool cv_small = ws_size >= (size_t)((char*)end_small - (char*)d_ws);
  const bool cv_wg    = ws_size >= (size_t)((char*)end_wg    - (char*)d_ws);
  const bool cv_enc   = ws_size >= (size_t)((char*)end_enc   - (char*)d_ws);

  hipMemsetAsync(acc_c, 0, (size_t)B_ * S_ * sizeof(float), stream);
  hipMemsetAsync(gis, 0, (size_t)2 * B_ * 3 * H_ * sizeof(float), stream); // gis+ghs

  dim3 blk(256);

  // ---- conversion passes ----
  build_x<<<80, blk, 0, stream>>>(input_idx, embed, weighted, x_bf);
  cvt_bf16<<<32, blk, 0, stream>>>(prev_state, ps_bf, B_ * H_ / 8);
  if (cv_small) {
    cvt_bf16<<<1024, blk, 0, stream>>>(Wc_w, wc_bf, H_ * 2 * H_ / 8);
    cvt_bf16<<<3840, blk, 0, stream>>>(gru_wi, wi_bf, 3 * H_ * (E_ + 2 * H_) / 8);
    cvt_bf16<<<1536, blk, 0, stream>>>(gru_wh, wh_bf, 3 * H_ * H_ / 8);
  }
  if (cv_wg)  cvt_bf16<<<8192, blk, 0, stream>>>(Wg_w, wg_bf, V_ * H_ / 8);
  if (cv_enc) cvt_bf16<<<8192, blk, 0, stream>>>(encoded, enc_bf, B_ * S_ * 2 * H_ / 8);

  // ---- gi = x @ gru_wi^T ; gh = prev_state @ gru_wh^T  (split-K x8) ----
  if (cv_small) {
    gemm_bf<2,0,0,0><<<dim3(24, 8), blk, 0, stream>>>(x_bf, nullptr, wi_bf, nullptr,
                                           nullptr, nullptr, gis, B_, 3 * H_, E_ + 2 * H_, 24, 320);
    gemm_bf<2,0,0,0><<<dim3(24, 8), blk, 0, stream>>>(ps_bf, nullptr, wh_bf, nullptr,
                                           nullptr, nullptr, ghs, B_, 3 * H_, H_, 24, 128);
  } else {
    gemm_bf<2,0,1,0><<<dim3(24, 8), blk, 0, stream>>>(x_bf, nullptr, nullptr, gru_wi,
                                           nullptr, nullptr, gis, B_, 3 * H_, E_ + 2 * H_, 24, 320);
    gemm_bf<2,0,1,0><<<dim3(24, 8), blk, 0, stream>>>(ps_bf, nullptr, nullptr, gru_wh,
                                           nullptr, nullptr, ghs, B_, 3 * H_, H_, 24, 128);
  }
  gru_combine<<<(B_ * H_) / 256, blk, 0, stream>>>(gis, ghs, prev_state, state, st_bf,
                                                   gru_bi, gru_bh);

  // ---- score_g = state @ Wg_w^T + Wg_b ----
  if (cv_wg)
    gemm_bf<0,0,0,0><<<393, blk, 0, stream>>>(st_bf, nullptr, wg_bf, nullptr,
                                            Wg_b, nullptr, score_g, B_, V_, H_, 393, H_);
  else
    gemm_bf<0,0,1,0><<<393, blk, 0, stream>>>(st_bf, nullptr, nullptr, Wg_w,
                                            Wg_b, nullptr, score_g, B_, V_, H_, 393, H_);

  // ---- acc_c[row] = sum_h tanh(encoded@Wc^T + bc) * state ----
  if (cv_enc && cv_small) {
    gemm256_accc<<<512, 512, 0, stream>>>(enc_bf, wc_bf, Wc_b, state, acc_c);
  } else if (cv_enc)
    gemm_bf<1,0,1,1><<<2048, blk, 0, stream>>>(enc_bf, nullptr, nullptr, Wc_w,
                                             Wc_b, state, acc_c, B_ * S_, H_, 2 * H_, 8, 2 * H_);
  else if (cv_small)
    gemm_bf<1,1,0,1><<<2048, blk, 0, stream>>>(nullptr, encoded, wc_bf, nullptr,
                                             Wc_b, state, acc_c, B_ * S_, H_, 2 * H_, 8, 2 * H_);
  else
    gemm_bf<1,1,1,1><<<2048, blk, 0, stream>>>(nullptr, encoded, nullptr, Wc_w,
                                             Wc_b, state, acc_c, B_ * S_, H_, 2 * H_, 8, 2 * H_);

  // ---- softmax + outputs ----
  softmax_chunk<<<dim3(NCH, B_), blk, 0, stream>>>(score_g, acc_c, encoded_idx, mc, lc);
  write_probg<<<dim3((VO_ + 255) / 256, B_), blk, 0, stream>>>(score_g, mc, lc, out0);
  scatter_weighted<<<B_, blk, 0, stream>>>(acc_c, encoded_idx, input_idx, encoded,
                                           mc, lc, out0, wout);
}